// Round 15
// baseline (766.765 us; speedup 1.0000x reference)
//
#include <hip/hip_runtime.h>

#define NEG_SLOPE 0.2f
#define BN_EPS 1e-5f
#define NDEG 64

typedef unsigned short u16;
typedef unsigned int u32;
typedef __bf16 bf16x8 __attribute__((ext_vector_type(8)));
typedef float f32x4 __attribute__((ext_vector_type(4)));

__device__ __forceinline__ u32 f2bf(float f) {
    u32 u = __float_as_uint(f);
    return (u + 0x7FFFu + ((u >> 16) & 1u)) >> 16;
}
__device__ __forceinline__ float bf2f(u32 h) { return __uint_as_float(h << 16); }
__device__ __forceinline__ float bfl(u32 p) { return __uint_as_float(p << 16); }
__device__ __forceinline__ float bfh(u32 p) { return __uint_as_float(p & 0xFFFF0000u); }

__device__ __forceinline__ void split8(const float4 f0, const float4 f1, uint4& vh, uint4& vl) {
    float f[8] = {f0.x, f0.y, f0.z, f0.w, f1.x, f1.y, f1.z, f1.w};
    u32 h[8], l[8];
    #pragma unroll
    for (int i = 0; i < 8; i++) { h[i] = f2bf(f[i]); l[i] = f2bf(f[i] - bf2f(h[i])); }
    vh = make_uint4(h[0] | (h[1] << 16), h[2] | (h[3] << 16), h[4] | (h[5] << 16), h[6] | (h[7] << 16));
    vl = make_uint4(l[0] | (l[1] << 16), l[2] | (l[3] << 16), l[4] | (l[5] << 16), l[6] | (l[7] << 16));
}

// ========== weight prep for layers 1-3 in one dispatch ==========
__global__ void wt_prep3(const float* __restrict__ W1, const float* __restrict__ W2,
                         const float* __restrict__ W3,
                         u16* __restrict__ h1, u16* __restrict__ l1,
                         u16* __restrict__ h2, u16* __restrict__ l2,
                         u16* __restrict__ h3, u16* __restrict__ l3) {
    int i = blockIdx.x * blockDim.x + threadIdx.x;
    const float* W; u16 *ph, *pl; int K, N, off;
    if (i < 32768)      { W = W1; ph = h1; pl = l1; K = 128; N = 256; off = i; }
    else if (i < 65536) { W = W2; ph = h2; pl = l2; K = 256; N = 128; off = i - 32768; }
    else if (i < 73728) { W = W3; ph = h3; pl = l3; K = 128; N = 64;  off = i - 65536; }
    else return;
    int k = off / N, n = off - k * N;
    float w = W[off];
    u32 h = f2bf(w);
    ph[n * K + k] = (u16)h;
    pl[n * K + k] = (u16)f2bf(w - bf2f(h));
}

// ========== split-bf16 MFMA GEMM -> bf16 head-major output ==========
template<int BN, int HMC, int AF32>
__launch_bounds__(256)
__global__ void gemm_mfma(const void* __restrict__ A_, const u16* __restrict__ Alo,
                          const u16* __restrict__ Bhi, const u16* __restrict__ Blo,
                          u16* __restrict__ Cbf, int M, int K, int N) {
    constexpr int FM = (BN == 128) ? 4 : 2;
    __shared__ uint4 sA[2][512];
    __shared__ uint4 sB[2][BN * 4];
    const int tid = threadIdx.x;
    const int bm = blockIdx.y * 128;
    const int bn = blockIdx.x * BN;
    const int lane = tid & 63;
    const int w = tid >> 6;
    const int wm = (BN == 128) ? (w >> 1) * 64 : w * 32;
    const int wn = (BN == 128) ? (w & 1) * 64 : 0;
    const int fr = lane & 15;
    const int fs = lane >> 4;
    f32x4 zero = {0.f, 0.f, 0.f, 0.f};
    f32x4 acc[FM][4];
    #pragma unroll
    for (int i = 0; i < FM; i++)
        #pragma unroll
        for (int j = 0; j < 4; j++) acc[i][j] = zero;

    const int r0 = tid >> 2;
    const int ss = tid & 3;
    const int r1 = r0 + 64;
    const int d0 = r0 * 4 + (ss ^ ((r0 >> 1) & 3));
    const int d1 = r1 * 4 + (ss ^ ((r1 >> 1) & 3));

    for (int k0 = 0; k0 < K; k0 += 32) {
        if constexpr (AF32) {
            const float* Af = (const float*)A_;
            int gr = bm + r0;
            uint4 vh = make_uint4(0,0,0,0), vl = make_uint4(0,0,0,0);
            if (gr < M) {
                float4 f0 = *(const float4*)(Af + (size_t)gr * K + k0 + ss * 8);
                float4 f1 = *(const float4*)(Af + (size_t)gr * K + k0 + ss * 8 + 4);
                split8(f0, f1, vh, vl);
            }
            sA[0][d0] = vh; sA[1][d0] = vl;
            gr = bm + r1;
            vh = make_uint4(0,0,0,0); vl = make_uint4(0,0,0,0);
            if (gr < M) {
                float4 f0 = *(const float4*)(Af + (size_t)gr * K + k0 + ss * 8);
                float4 f1 = *(const float4*)(Af + (size_t)gr * K + k0 + ss * 8 + 4);
                split8(f0, f1, vh, vl);
            }
            sA[0][d1] = vh; sA[1][d1] = vl;
        } else {
            const u16* Ahi = (const u16*)A_;
            int gr = bm + r0;
            uint4 vh = make_uint4(0,0,0,0), vl = make_uint4(0,0,0,0);
            if (gr < M) {
                vh = *(const uint4*)(Ahi + (size_t)gr * K + k0 + ss * 8);
                vl = *(const uint4*)(Alo + (size_t)gr * K + k0 + ss * 8);
            }
            sA[0][d0] = vh; sA[1][d0] = vl;
            gr = bm + r1;
            vh = make_uint4(0,0,0,0); vl = make_uint4(0,0,0,0);
            if (gr < M) {
                vh = *(const uint4*)(Ahi + (size_t)gr * K + k0 + ss * 8);
                vl = *(const uint4*)(Alo + (size_t)gr * K + k0 + ss * 8);
            }
            sA[0][d1] = vh; sA[1][d1] = vl;
        }
        {
            int gr = bn + r0;
            sB[0][d0] = *(const uint4*)(Bhi + (size_t)gr * K + k0 + ss * 8);
            sB[1][d0] = *(const uint4*)(Blo + (size_t)gr * K + k0 + ss * 8);
            if constexpr (BN == 128) {
                gr = bn + r1;
                sB[0][d1] = *(const uint4*)(Bhi + (size_t)gr * K + k0 + ss * 8);
                sB[1][d1] = *(const uint4*)(Blo + (size_t)gr * K + k0 + ss * 8);
            }
        }
        __syncthreads();
        bf16x8 ah[FM], al[FM], bh[4], bl[4];
        #pragma unroll
        for (int mi = 0; mi < FM; mi++) {
            int row = wm + mi * 16 + fr;
            int idx = row * 4 + (fs ^ ((row >> 1) & 3));
            ah[mi] = *reinterpret_cast<const bf16x8*>(&sA[0][idx]);
            al[mi] = *reinterpret_cast<const bf16x8*>(&sA[1][idx]);
        }
        #pragma unroll
        for (int ni = 0; ni < 4; ni++) {
            int row = wn + ni * 16 + fr;
            int idx = row * 4 + (fs ^ ((row >> 1) & 3));
            bh[ni] = *reinterpret_cast<const bf16x8*>(&sB[0][idx]);
            bl[ni] = *reinterpret_cast<const bf16x8*>(&sB[1][idx]);
        }
        #pragma unroll
        for (int mi = 0; mi < FM; mi++)
            #pragma unroll
            for (int ni = 0; ni < 4; ni++) {
                acc[mi][ni] = __builtin_amdgcn_mfma_f32_16x16x32_bf16(ah[mi], bh[ni], acc[mi][ni], 0, 0, 0);
                acc[mi][ni] = __builtin_amdgcn_mfma_f32_16x16x32_bf16(ah[mi], bl[ni], acc[mi][ni], 0, 0, 0);
                acc[mi][ni] = __builtin_amdgcn_mfma_f32_16x16x32_bf16(al[mi], bh[ni], acc[mi][ni], 0, 0, 0);
            }
        __syncthreads();
    }
    #pragma unroll
    for (int mi = 0; mi < FM; mi++) {
        #pragma unroll
        for (int ni = 0; ni < 4; ni++) {
            int colg = bn + wn + ni * 16 + fr;
            int rbase = bm + wm + mi * 16 + fs * 4;
            #pragma unroll
            for (int r = 0; r < 4; r++) {
                int rw = rbase + r;
                if (rw >= M) continue;
                u16 val = (u16)f2bf(acc[mi][ni][r]);
                if constexpr (HMC > 0) {
                    int hh2 = colg / HMC, cc2 = colg - hh2 * HMC;
                    Cbf[((size_t)hh2 * M + rw) * HMC + cc2] = val;
                } else {
                    Cbf[(size_t)rw * N + colg] = val;
                }
            }
        }
    }
}

// ================= small GEMM for layer 4: K=64, N=16 -> bf16 out =================
__launch_bounds__(256)
__global__ void gemm_k64n16(const float* __restrict__ A, const float* __restrict__ B,
                            u16* __restrict__ Cbf, int M) {
    __shared__ float As[64][68];
    __shared__ float Bs[64][16];
    const int tid = threadIdx.x;
    const int bm = blockIdx.x * 64;
    {
        int r = tid >> 2, c = (tid & 3) << 2;
        *reinterpret_cast<float4*>(&Bs[r][c]) = *reinterpret_cast<const float4*>(&B[r * 16 + c]);
    }
    #pragma unroll
    for (int p = 0; p < 4; p++) {
        int m = (tid >> 4) + p * 16;
        int c = (tid & 15) << 2;
        int gm = bm + m;
        float4 v = make_float4(0.f, 0.f, 0.f, 0.f);
        if (gm < M) v = *reinterpret_cast<const float4*>(&A[(size_t)gm * 64 + c]);
        *reinterpret_cast<float4*>(&As[m][c]) = v;
    }
    __syncthreads();
    const int tc = tid & 15;
    const int r0 = tid >> 4;
    float acc[4] = {};
    #pragma unroll
    for (int k4 = 0; k4 < 16; k4++) {
        float b0 = Bs[4 * k4 + 0][tc];
        float b1 = Bs[4 * k4 + 1][tc];
        float b2 = Bs[4 * k4 + 2][tc];
        float b3 = Bs[4 * k4 + 3][tc];
        #pragma unroll
        for (int i = 0; i < 4; i++) {
            float4 av = *reinterpret_cast<const float4*>(&As[r0 + i * 16][4 * k4]);
            acc[i] += av.x * b0 + av.y * b1 + av.z * b2 + av.w * b3;
        }
    }
    #pragma unroll
    for (int i = 0; i < 4; i++) {
        int m = bm + r0 + i * 16;
        if (m < M) Cbf[(size_t)m * 16 + tc] = (u16)f2bf(acc[i]);
    }
}

// ========== per-node attention scores (head-major h; head-major es/ed) ==========
__global__ void scores_kernel(const u16* __restrict__ h,
                              const float* __restrict__ asrc,
                              const float* __restrict__ adst,
                              float* __restrict__ es, float* __restrict__ ed,
                              int Nn, int H, int C) {
    int idx = blockIdx.x * blockDim.x + threadIdx.x;
    if (idx >= Nn * H) return;
    int n = idx / H, hh = idx % H;
    const u16* hp = h + ((size_t)hh * Nn + n) * C;
    const float4* ap = reinterpret_cast<const float4*>(asrc + hh * C);
    const float4* bp = reinterpret_cast<const float4*>(adst + hh * C);
    float s = 0.f, d = 0.f;
    for (int c4 = 0; c4 < C / 4; c4++) {
        uint2 pv = *reinterpret_cast<const uint2*>(hp + 4 * c4);
        float v0 = bfl(pv.x), v1 = bfh(pv.x), v2 = bfl(pv.y), v3 = bfh(pv.y);
        float4 a = ap[c4], b = bp[c4];
        s += v0 * a.x + v1 * a.y + v2 * a.z + v3 * a.w;
        d += v0 * b.x + v1 * b.y + v2 * b.z + v3 * b.w;
    }
    es[(size_t)hh * Nn + n] = s;
    ed[(size_t)hh * Nn + n] = d;
}

// ================= CSR build =================
__global__ void hist_kernel(const int* __restrict__ dst, int* __restrict__ counts,
                            int E0, int Etot) {
    int e = blockIdx.x * blockDim.x + threadIdx.x;
    if (e >= Etot) return;
    int d_ = (e < E0) ? dst[e] : e - E0;
    atomicAdd(&counts[d_], 1);
}

__global__ void scan_kernel(int* __restrict__ counts, int* __restrict__ row_ptr, int Nn) {
    __shared__ int wsum[16];
    __shared__ int chunk_total;
    __shared__ int carry_s;
    const int tid = threadIdx.x;
    const int lane = tid & 63;
    const int wid = tid >> 6;
    if (tid == 0) carry_s = 0;
    __syncthreads();
    for (int base = 0; base < Nn; base += 1024) {
        int i = base + tid;
        int v = (i < Nn) ? counts[i] : 0;
        int iv = v;
        #pragma unroll
        for (int off = 1; off < 64; off <<= 1) {
            int t = __shfl_up(iv, off, 64);
            if (lane >= off) iv += t;
        }
        if (lane == 63) wsum[wid] = iv;
        __syncthreads();
        if (tid == 0) {
            int s = 0;
            #pragma unroll
            for (int k = 0; k < 16; k++) { int t = wsum[k]; wsum[k] = s; s += t; }
            chunk_total = s;
        }
        __syncthreads();
        if (i < Nn) {
            int ex = carry_s + wsum[wid] + (iv - v);
            row_ptr[i] = ex;
            counts[i] = ex;
        }
        __syncthreads();
        if (tid == 0) carry_s += chunk_total;
        __syncthreads();
    }
    if (tid == 0) row_ptr[Nn] = carry_s;
}

__global__ void scatter_kernel(const int* __restrict__ src, const int* __restrict__ dst,
                               int* __restrict__ cursor, int* __restrict__ col,
                               int E0, int Etot) {
    int e = blockIdx.x * blockDim.x + threadIdx.x;
    if (e >= Etot) return;
    int d_ = (e < E0) ? dst[e] : e - E0;
    int s_ = (e < E0) ? src[e] : e - E0;
    int pos = atomicAdd(&cursor[d_], 1);
    col[pos] = s_;
}

// ================= degree-sorted node permutation (counting sort, 64 buckets) =================
__global__ void deg_hist(const int* __restrict__ row_ptr, int* __restrict__ dbk, int Nn) {
    int n = blockIdx.x * blockDim.x + threadIdx.x;
    if (n >= Nn) return;
    int d = row_ptr[n + 1] - row_ptr[n];
    if (d > NDEG - 1) d = NDEG - 1;
    atomicAdd(&dbk[d], 1);
}
__global__ void deg_scan(int* __restrict__ dbk, int* __restrict__ dcur) {
    if (threadIdx.x == 0 && blockIdx.x == 0) {
        int s = 0;
        for (int i = 0; i < NDEG; i++) { int t = dbk[i]; dcur[i] = s; s += t; }
    }
}
__global__ void deg_scatter(const int* __restrict__ row_ptr, int* __restrict__ dcur,
                            int* __restrict__ perm, int Nn) {
    int n = blockIdx.x * blockDim.x + threadIdx.x;
    if (n >= Nn) return;
    int d = row_ptr[n + 1] - row_ptr[n];
    if (d > NDEG - 1) d = NDEG - 1;
    int pos = atomicAdd(&dcur[d], 1);
    perm[pos] = n;
}

// ========== fused softmax + aggregate + bias + ELU + BN (inline exp, no LDS) ==========
// NT lanes per (node, head), VEC = C/NT channels per lane.
// XCD affinity: head = blockIdx.x & 7 (XCD = wgid % 8 round-robin) -> per-head h slice L2-resident.
// Degree-sorted perm: co-resident groups have equal degree -> no wave divergence.
template<int H, int C, int NT, int DO_ELU, int OUT_HILO>
__launch_bounds__(256)
__global__ void gat_fused(const int* __restrict__ perm,
                          const int* __restrict__ row_ptr, const int* __restrict__ col,
                          const float* __restrict__ es, const float* __restrict__ ed,
                          const u16* __restrict__ h16, float* __restrict__ outf,
                          u16* __restrict__ outh, u16* __restrict__ outl,
                          const float* __restrict__ bias, const float* __restrict__ g,
                          const float* __restrict__ be, const float* __restrict__ rm,
                          const float* __restrict__ rv, int Nn) {
    constexpr int Dout = H * C;
    constexpr int VEC = C / NT;          // 8 (uint4) or 4 (uint2)
    constexpr int NPB = 256 / NT;
    const int tid = threadIdx.x;
    const int bx = blockIdx.x;
    const int hh = (H == 8) ? (bx & 7) : 0;
    const int nb = (H == 8) ? (bx >> 3) : bx;
    const int gid = nb * NPB + tid / NT;
    const int t = tid % NT;
    if (gid >= Nn) return;
    const int node = perm[gid];
    const int jb = row_ptr[node], je = row_ptr[node + 1];
    const float* esh = es + (size_t)hh * Nn;
    const float edv = ed[(size_t)hh * Nn + node];
    const u16* hb = h16 + (size_t)hh * Nn * C + t * VEC;
    float acc[VEC] = {};
    float den = 0.f;
    int j = jb;
    for (; j + 4 <= je; j += 4) {
        int s0 = col[j], s1 = col[j + 1], s2 = col[j + 2], s3 = col[j + 3];
        float e0 = esh[s0] + edv, e1 = esh[s1] + edv, e2 = esh[s2] + edv, e3 = esh[s3] + edv;
        e0 = (e0 >= 0.f) ? e0 : NEG_SLOPE * e0;
        e1 = (e1 >= 0.f) ? e1 : NEG_SLOPE * e1;
        e2 = (e2 >= 0.f) ? e2 : NEG_SLOPE * e2;
        e3 = (e3 >= 0.f) ? e3 : NEG_SLOPE * e3;
        float w0 = __expf(e0), w1 = __expf(e1), w2 = __expf(e2), w3 = __expf(e3);
        den += (w0 + w1) + (w2 + w3);
        if constexpr (VEC == 8) {
            uint4 p0 = *reinterpret_cast<const uint4*>(hb + (size_t)s0 * C);
            uint4 p1 = *reinterpret_cast<const uint4*>(hb + (size_t)s1 * C);
            uint4 p2 = *reinterpret_cast<const uint4*>(hb + (size_t)s2 * C);
            uint4 p3 = *reinterpret_cast<const uint4*>(hb + (size_t)s3 * C);
            acc[0] += w0 * bfl(p0.x) + w1 * bfl(p1.x) + w2 * bfl(p2.x) + w3 * bfl(p3.x);
            acc[1] += w0 * bfh(p0.x) + w1 * bfh(p1.x) + w2 * bfh(p2.x) + w3 * bfh(p3.x);
            acc[2] += w0 * bfl(p0.y) + w1 * bfl(p1.y) + w2 * bfl(p2.y) + w3 * bfl(p3.y);
            acc[3] += w0 * bfh(p0.y) + w1 * bfh(p1.y) + w2 * bfh(p2.y) + w3 * bfh(p3.y);
            acc[4] += w0 * bfl(p0.z) + w1 * bfl(p1.z) + w2 * bfl(p2.z) + w3 * bfl(p3.z);
            acc[5] += w0 * bfh(p0.z) + w1 * bfh(p1.z) + w2 * bfh(p2.z) + w3 * bfh(p3.z);
            acc[6] += w0 * bfl(p0.w) + w1 * bfl(p1.w) + w2 * bfl(p2.w) + w3 * bfl(p3.w);
            acc[7] += w0 * bfh(p0.w) + w1 * bfh(p1.w) + w2 * bfh(p2.w) + w3 * bfh(p3.w);
        } else {
            uint2 p0 = *reinterpret_cast<const uint2*>(hb + (size_t)s0 * C);
            uint2 p1 = *reinterpret_cast<const uint2*>(hb + (size_t)s1 * C);
            uint2 p2 = *reinterpret_cast<const uint2*>(hb + (size_t)s2 * C);
            uint2 p3 = *reinterpret_cast<const uint2*>(hb + (size_t)s3 * C);
            acc[0] += w0 * bfl(p0.x) + w1 * bfl(p1.x) + w2 * bfl(p2.x) + w3 * bfl(p3.x);
            acc[1] += w0 * bfh(p0.x) + w1 * bfh(p1.x) + w2 * bfh(p2.x) + w3 * bfh(p3.x);
            acc[2] += w0 * bfl(p0.y) + w1 * bfl(p1.y) + w2 * bfl(p2.y) + w3 * bfl(p3.y);
            acc[3] += w0 * bfh(p0.y) + w1 * bfh(p1.y) + w2 * bfh(p2.y) + w3 * bfh(p3.y);
        }
    }
    for (; j < je; j++) {
        int s = col[j];
        float a = esh[s] + edv;
        a = (a >= 0.f) ? a : NEG_SLOPE * a;
        float w = __expf(a);
        den += w;
        if constexpr (VEC == 8) {
            uint4 pv = *reinterpret_cast<const uint4*>(hb + (size_t)s * C);
            acc[0] += w * bfl(pv.x); acc[1] += w * bfh(pv.x);
            acc[2] += w * bfl(pv.y); acc[3] += w * bfh(pv.y);
            acc[4] += w * bfl(pv.z); acc[5] += w * bfh(pv.z);
            acc[6] += w * bfl(pv.w); acc[7] += w * bfh(pv.w);
        } else {
            uint2 pv = *reinterpret_cast<const uint2*>(hb + (size_t)s * C);
            acc[0] += w * bfl(pv.x); acc[1] += w * bfh(pv.x);
            acc[2] += w * bfl(pv.y); acc[3] += w * bfh(pv.y);
        }
    }
    const float inv = 1.f / (den + 1e-16f);
    const int jc = hh * C + t * VEC;
    float res[VEC];
    #pragma unroll
    for (int v = 0; v < VEC; v++) {
        float y = acc[v] * inv + bias[jc + v];
        if (DO_ELU) y = (y > 0.f) ? y : expm1f(y);
        y = (y - rm[jc + v]) * rsqrtf(rv[jc + v] + BN_EPS) * g[jc + v] + be[jc + v];
        res[v] = y;
    }
    if constexpr (OUT_HILO) {
        u32 rh[VEC], rl[VEC];
        #pragma unroll
        for (int v = 0; v < VEC; v++) {
            rh[v] = f2bf(res[v]);
            rl[v] = f2bf(res[v] - bf2f(rh[v]));
        }
        if constexpr (VEC == 8) {
            uint4 ph = make_uint4(rh[0] | (rh[1] << 16), rh[2] | (rh[3] << 16),
                                  rh[4] | (rh[5] << 16), rh[6] | (rh[7] << 16));
            uint4 pl = make_uint4(rl[0] | (rl[1] << 16), rl[2] | (rl[3] << 16),
                                  rl[4] | (rl[5] << 16), rl[6] | (rl[7] << 16));
            *reinterpret_cast<uint4*>(outh + (size_t)node * Dout + jc) = ph;
            *reinterpret_cast<uint4*>(outl + (size_t)node * Dout + jc) = pl;
        } else {
            uint2 ph = make_uint2(rh[0] | (rh[1] << 16), rh[2] | (rh[3] << 16));
            uint2 pl = make_uint2(rl[0] | (rl[1] << 16), rl[2] | (rl[3] << 16));
            *reinterpret_cast<uint2*>(outh + (size_t)node * Dout + jc) = ph;
            *reinterpret_cast<uint2*>(outl + (size_t)node * Dout + jc) = pl;
        }
    } else {
        float* op = outf + (size_t)node * Dout + jc;
        if constexpr (VEC == 8) {
            *reinterpret_cast<float4*>(op) = make_float4(res[0], res[1], res[2], res[3]);
            *reinterpret_cast<float4*>(op + 4) = make_float4(res[4], res[5], res[6], res[7]);
        } else {
            *reinterpret_cast<float4*>(op) = make_float4(res[0], res[1], res[2], res[3]);
        }
    }
}

extern "C" void kernel_launch(void* const* d_in, const int* in_sizes, int n_in,
                              void* d_out, int out_size, void* d_ws, size_t ws_size,
                              hipStream_t stream) {
    const float* x = (const float*)d_in[0];
    const int* src = (const int*)d_in[1];
    const int* dst = (const int*)d_in[2];
    const int Nn = in_sizes[0] / 128;   // 50000
    const int E0 = in_sizes[1];         // 400000
    const int Etot = E0 + Nn;

    // ---- workspace layout ----
    u16* A0 = (u16*)d_ws;                                  // Nn*512 u16: Y1H/Y1L or out3 fp32
    u16* Bh = A0 + (size_t)Nn * 512;                       // Nn*256 u16: h (head-major)
    u16* Ch = Bh + (size_t)Nn * 256;                       // Nn*256 u16: Y2H/Y2L
    float* es = (float*)(Ch + (size_t)Nn * 256);           // Nn*8 (head-major)
    float* ed = es + (size_t)Nn * 8;                       // Nn*8
    int* row_ptr = (int*)(ed + (size_t)Nn * 8);            // Nn+1
    int* cursor  = row_ptr + (Nn + 1);                     // Nn
    int* col     = cursor + Nn;                            // Etot
    u16* wth1 = (u16*)(col + Etot);
    u16* wtl1 = wth1 + 32768;
    u16* wth2 = wtl1 + 32768;
    u16* wtl2 = wth2 + 32768;
    u16* wth3 = wtl2 + 32768;
    u16* wtl3 = wth3 + 8192;
    int* perm = (int*)(wtl3 + 8192);                       // Nn
    int* dbk  = perm + Nn;                                 // NDEG
    int* dcur = dbk + NDEG;                                // NDEG

    u16* Y1H = A0;
    u16* Y1L = A0 + (size_t)Nn * 256;
    u16* Y2H = Ch;
    u16* Y2L = Ch + (size_t)Nn * 128;
    float* out3 = (float*)A0;

    // ---- CSR build ----
    hipMemsetAsync(cursor, 0, sizeof(int) * Nn, stream);
    hist_kernel<<<(Etot + 255) / 256, 256, 0, stream>>>(dst, cursor, E0, Etot);
    scan_kernel<<<1, 1024, 0, stream>>>(cursor, row_ptr, Nn);
    scatter_kernel<<<(Etot + 255) / 256, 256, 0, stream>>>(src, dst, cursor, col, E0, Etot);

    // ---- degree-sorted permutation ----
    hipMemsetAsync(dbk, 0, sizeof(int) * NDEG, stream);
    deg_hist<<<(Nn + 255) / 256, 256, 0, stream>>>(row_ptr, dbk, Nn);
    deg_scan<<<1, 64, 0, stream>>>(dbk, dcur);
    deg_scatter<<<(Nn + 255) / 256, 256, 0, stream>>>(row_ptr, dcur, perm, Nn);

    const int gy128 = (Nn + 127) / 128;

    const float* const* p1 = (const float* const*)(d_in + 3);
    const float* const* p2 = (const float* const*)(d_in + 11);
    const float* const* p3 = (const float* const*)(d_in + 19);
    const float* const* p4 = (const float* const*)(d_in + 27);

    wt_prep3<<<288, 256, 0, stream>>>(p1[0], p2[0], p3[0], wth1, wtl1, wth2, wtl2, wth3, wtl3);

    // ---------------- layer 1: K=128 -> Dout=256 (H=8,C=32) ----------------
    gemm_mfma<128, 32, 1><<<dim3(2, gy128), 256, 0, stream>>>(x, nullptr, wth1, wtl1, Bh, Nn, 128, 256);
    scores_kernel<<<(Nn * 8 + 255) / 256, 256, 0, stream>>>(Bh, p1[1], p1[2], es, ed, Nn, 8, 32);
    gat_fused<8, 32, 4, 1, 1><<<dim3(((Nn + 63) / 64) * 8), 256, 0, stream>>>(
        perm, row_ptr, col, es, ed, Bh, nullptr, Y1H, Y1L, p1[3], p1[4], p1[5], p1[6], p1[7], Nn);

    // ---------------- layer 2: K=256 -> Dout=128 (H=8,C=16) ----------------
    gemm_mfma<128, 16, 0><<<dim3(1, gy128), 256, 0, stream>>>(Y1H, Y1L, wth2, wtl2, Bh, Nn, 256, 128);
    scores_kernel<<<(Nn * 8 + 255) / 256, 256, 0, stream>>>(Bh, p2[1], p2[2], es, ed, Nn, 8, 16);
    gat_fused<8, 16, 2, 1, 1><<<dim3(((Nn + 127) / 128) * 8), 256, 0, stream>>>(
        perm, row_ptr, col, es, ed, Bh, nullptr, Y2H, Y2L, p2[3], p2[4], p2[5], p2[6], p2[7], Nn);

    // ---------------- layer 3: K=128 -> Dout=64 (H=8,C=8) ----------------
    gemm_mfma<64, 8, 0><<<dim3(1, gy128), 256, 0, stream>>>(Y2H, Y2L, wth3, wtl3, Bh, Nn, 128, 64);
    scores_kernel<<<(Nn * 8 + 255) / 256, 256, 0, stream>>>(Bh, p3[1], p3[2], es, ed, Nn, 8, 8);
    gat_fused<8, 8, 2, 1, 0><<<dim3(((Nn + 127) / 128) * 8), 256, 0, stream>>>(
        perm, row_ptr, col, es, ed, Bh, out3, nullptr, nullptr, p3[3], p3[4], p3[5], p3[6], p3[7], Nn);

    // ---------------- layer 4: K=64 -> Dout=16 (H=1,C=16) ----------------
    gemm_k64n16<<<(Nn + 63) / 64, 256, 0, stream>>>(out3, p4[0], Bh, Nn);
    scores_kernel<<<(Nn + 255) / 256, 256, 0, stream>>>(Bh, p4[1], p4[2], es, ed, Nn, 1, 16);
    gat_fused<1, 16, 2, 0, 0><<<dim3((Nn + 127) / 128), 256, 0, stream>>>(
        perm, row_ptr, col, es, ed, Bh, (float*)d_out, nullptr, nullptr, p4[3], p4[4], p4[5], p4[6], p4[7], Nn);
}

// Round 17
// 375.843 us; speedup vs baseline: 2.0401x; 2.0401x over previous
//
#include <hip/hip_runtime.h>

#define NEG_SLOPE 0.2f
#define BN_EPS 1e-5f

typedef unsigned short u16;
typedef unsigned int u32;
typedef __bf16 bf16x8 __attribute__((ext_vector_type(8)));
typedef float f32x4 __attribute__((ext_vector_type(4)));

__device__ __forceinline__ u32 f2bf(float f) {
    u32 u = __float_as_uint(f);
    return (u + 0x7FFFu + ((u >> 16) & 1u)) >> 16;
}
__device__ __forceinline__ float bf2f(u32 h) { return __uint_as_float(h << 16); }
__device__ __forceinline__ float bfl(u32 p) { return __uint_as_float(p << 16); }
__device__ __forceinline__ float bfh(u32 p) { return __uint_as_float(p & 0xFFFF0000u); }

__device__ __forceinline__ void split8(const float4 f0, const float4 f1, uint4& vh, uint4& vl) {
    float f[8] = {f0.x, f0.y, f0.z, f0.w, f1.x, f1.y, f1.z, f1.w};
    u32 h[8], l[8];
    #pragma unroll
    for (int i = 0; i < 8; i++) { h[i] = f2bf(f[i]); l[i] = f2bf(f[i] - bf2f(h[i])); }
    vh = make_uint4(h[0] | (h[1] << 16), h[2] | (h[3] << 16), h[4] | (h[5] << 16), h[6] | (h[7] << 16));
    vl = make_uint4(l[0] | (l[1] << 16), l[2] | (l[3] << 16), l[4] | (l[5] << 16), l[6] | (l[7] << 16));
}

// ========== weight prep for layers 1-3 in one dispatch ==========
__global__ void wt_prep3(const float* __restrict__ W1, const float* __restrict__ W2,
                         const float* __restrict__ W3,
                         u16* __restrict__ h1, u16* __restrict__ l1,
                         u16* __restrict__ h2, u16* __restrict__ l2,
                         u16* __restrict__ h3, u16* __restrict__ l3) {
    int i = blockIdx.x * blockDim.x + threadIdx.x;
    const float* W; u16 *ph, *pl; int K, N, off;
    if (i < 32768)      { W = W1; ph = h1; pl = l1; K = 128; N = 256; off = i; }
    else if (i < 65536) { W = W2; ph = h2; pl = l2; K = 256; N = 128; off = i - 32768; }
    else if (i < 73728) { W = W3; ph = h3; pl = l3; K = 128; N = 64;  off = i - 65536; }
    else return;
    int k = off / N, n = off - k * N;
    float w = W[off];
    u32 h = f2bf(w);
    ph[n * K + k] = (u16)h;
    pl[n * K + k] = (u16)f2bf(w - bf2f(h));
}

// ========== split-bf16 MFMA GEMM -> bf16 head-major output ==========
// AF32=1: A is fp32 [M][K], hi/lo split in-register while staging.
template<int BN, int HMC, int AF32>
__launch_bounds__(256)
__global__ void gemm_mfma(const void* __restrict__ A_, const u16* __restrict__ Alo,
                          const u16* __restrict__ Bhi, const u16* __restrict__ Blo,
                          u16* __restrict__ Cbf, int M, int K, int N) {
    constexpr int FM = (BN == 128) ? 4 : 2;
    __shared__ uint4 sA[2][512];
    __shared__ uint4 sB[2][BN * 4];
    const int tid = threadIdx.x;
    const int bm = blockIdx.y * 128;
    const int bn = blockIdx.x * BN;
    const int lane = tid & 63;
    const int w = tid >> 6;
    const int wm = (BN == 128) ? (w >> 1) * 64 : w * 32;
    const int wn = (BN == 128) ? (w & 1) * 64 : 0;
    const int fr = lane & 15;
    const int fs = lane >> 4;
    f32x4 zero = {0.f, 0.f, 0.f, 0.f};
    f32x4 acc[FM][4];
    #pragma unroll
    for (int i = 0; i < FM; i++)
        #pragma unroll
        for (int j = 0; j < 4; j++) acc[i][j] = zero;

    const int r0 = tid >> 2;
    const int ss = tid & 3;
    const int r1 = r0 + 64;
    const int d0 = r0 * 4 + (ss ^ ((r0 >> 1) & 3));
    const int d1 = r1 * 4 + (ss ^ ((r1 >> 1) & 3));

    for (int k0 = 0; k0 < K; k0 += 32) {
        if constexpr (AF32) {
            const float* Af = (const float*)A_;
            int gr = bm + r0;
            uint4 vh = make_uint4(0,0,0,0), vl = make_uint4(0,0,0,0);
            if (gr < M) {
                float4 f0 = *(const float4*)(Af + (size_t)gr * K + k0 + ss * 8);
                float4 f1 = *(const float4*)(Af + (size_t)gr * K + k0 + ss * 8 + 4);
                split8(f0, f1, vh, vl);
            }
            sA[0][d0] = vh; sA[1][d0] = vl;
            gr = bm + r1;
            vh = make_uint4(0,0,0,0); vl = make_uint4(0,0,0,0);
            if (gr < M) {
                float4 f0 = *(const float4*)(Af + (size_t)gr * K + k0 + ss * 8);
                float4 f1 = *(const float4*)(Af + (size_t)gr * K + k0 + ss * 8 + 4);
                split8(f0, f1, vh, vl);
            }
            sA[0][d1] = vh; sA[1][d1] = vl;
        } else {
            const u16* Ahi = (const u16*)A_;
            int gr = bm + r0;
            uint4 vh = make_uint4(0,0,0,0), vl = make_uint4(0,0,0,0);
            if (gr < M) {
                vh = *(const uint4*)(Ahi + (size_t)gr * K + k0 + ss * 8);
                vl = *(const uint4*)(Alo + (size_t)gr * K + k0 + ss * 8);
            }
            sA[0][d0] = vh; sA[1][d0] = vl;
            gr = bm + r1;
            vh = make_uint4(0,0,0,0); vl = make_uint4(0,0,0,0);
            if (gr < M) {
                vh = *(const uint4*)(Ahi + (size_t)gr * K + k0 + ss * 8);
                vl = *(const uint4*)(Alo + (size_t)gr * K + k0 + ss * 8);
            }
            sA[0][d1] = vh; sA[1][d1] = vl;
        }
        {
            int gr = bn + r0;
            sB[0][d0] = *(const uint4*)(Bhi + (size_t)gr * K + k0 + ss * 8);
            sB[1][d0] = *(const uint4*)(Blo + (size_t)gr * K + k0 + ss * 8);
            if constexpr (BN == 128) {
                gr = bn + r1;
                sB[0][d1] = *(const uint4*)(Bhi + (size_t)gr * K + k0 + ss * 8);
                sB[1][d1] = *(const uint4*)(Blo + (size_t)gr * K + k0 + ss * 8);
            }
        }
        __syncthreads();
        bf16x8 ah[FM], al[FM], bh[4], bl[4];
        #pragma unroll
        for (int mi = 0; mi < FM; mi++) {
            int row = wm + mi * 16 + fr;
            int idx = row * 4 + (fs ^ ((row >> 1) & 3));
            ah[mi] = *reinterpret_cast<const bf16x8*>(&sA[0][idx]);
            al[mi] = *reinterpret_cast<const bf16x8*>(&sA[1][idx]);
        }
        #pragma unroll
        for (int ni = 0; ni < 4; ni++) {
            int row = wn + ni * 16 + fr;
            int idx = row * 4 + (fs ^ ((row >> 1) & 3));
            bh[ni] = *reinterpret_cast<const bf16x8*>(&sB[0][idx]);
            bl[ni] = *reinterpret_cast<const bf16x8*>(&sB[1][idx]);
        }
        #pragma unroll
        for (int mi = 0; mi < FM; mi++)
            #pragma unroll
            for (int ni = 0; ni < 4; ni++) {
                acc[mi][ni] = __builtin_amdgcn_mfma_f32_16x16x32_bf16(ah[mi], bh[ni], acc[mi][ni], 0, 0, 0);
                acc[mi][ni] = __builtin_amdgcn_mfma_f32_16x16x32_bf16(ah[mi], bl[ni], acc[mi][ni], 0, 0, 0);
                acc[mi][ni] = __builtin_amdgcn_mfma_f32_16x16x32_bf16(al[mi], bh[ni], acc[mi][ni], 0, 0, 0);
            }
        __syncthreads();
    }
    #pragma unroll
    for (int mi = 0; mi < FM; mi++) {
        #pragma unroll
        for (int ni = 0; ni < 4; ni++) {
            int colg = bn + wn + ni * 16 + fr;
            int rbase = bm + wm + mi * 16 + fs * 4;
            #pragma unroll
            for (int r = 0; r < 4; r++) {
                int rw = rbase + r;
                if (rw >= M) continue;
                u16 val = (u16)f2bf(acc[mi][ni][r]);
                if constexpr (HMC > 0) {
                    int hh2 = colg / HMC, cc2 = colg - hh2 * HMC;
                    Cbf[((size_t)hh2 * M + rw) * HMC + cc2] = val;
                } else {
                    Cbf[(size_t)rw * N + colg] = val;
                }
            }
        }
    }
}

// ================= small GEMM for layer 4: K=64, N=16 -> bf16 out =================
__launch_bounds__(256)
__global__ void gemm_k64n16(const float* __restrict__ A, const float* __restrict__ B,
                            u16* __restrict__ Cbf, int M) {
    __shared__ float As[64][68];
    __shared__ float Bs[64][16];
    const int tid = threadIdx.x;
    const int bm = blockIdx.x * 64;
    {
        int r = tid >> 2, c = (tid & 3) << 2;
        *reinterpret_cast<float4*>(&Bs[r][c]) = *reinterpret_cast<const float4*>(&B[r * 16 + c]);
    }
    #pragma unroll
    for (int p = 0; p < 4; p++) {
        int m = (tid >> 4) + p * 16;
        int c = (tid & 15) << 2;
        int gm = bm + m;
        float4 v = make_float4(0.f, 0.f, 0.f, 0.f);
        if (gm < M) v = *reinterpret_cast<const float4*>(&A[(size_t)gm * 64 + c]);
        *reinterpret_cast<float4*>(&As[m][c]) = v;
    }
    __syncthreads();
    const int tc = tid & 15;
    const int r0 = tid >> 4;
    float acc[4] = {};
    #pragma unroll
    for (int k4 = 0; k4 < 16; k4++) {
        float b0 = Bs[4 * k4 + 0][tc];
        float b1 = Bs[4 * k4 + 1][tc];
        float b2 = Bs[4 * k4 + 2][tc];
        float b3 = Bs[4 * k4 + 3][tc];
        #pragma unroll
        for (int i = 0; i < 4; i++) {
            float4 av = *reinterpret_cast<const float4*>(&As[r0 + i * 16][4 * k4]);
            acc[i] += av.x * b0 + av.y * b1 + av.z * b2 + av.w * b3;
        }
    }
    #pragma unroll
    for (int i = 0; i < 4; i++) {
        int m = bm + r0 + i * 16;
        if (m < M) Cbf[(size_t)m * 16 + tc] = (u16)f2bf(acc[i]);
    }
}

// ========== per-node attention scores (head-major h; head-major es/ed) ==========
__global__ void scores_kernel(const u16* __restrict__ h,
                              const float* __restrict__ asrc,
                              const float* __restrict__ adst,
                              float* __restrict__ es, float* __restrict__ ed,
                              int Nn, int H, int C) {
    int idx = blockIdx.x * blockDim.x + threadIdx.x;
    if (idx >= Nn * H) return;
    int n = idx / H, hh = idx % H;
    const u16* hp = h + ((size_t)hh * Nn + n) * C;
    const float4* ap = reinterpret_cast<const float4*>(asrc + hh * C);
    const float4* bp = reinterpret_cast<const float4*>(adst + hh * C);
    float s = 0.f, d = 0.f;
    for (int c4 = 0; c4 < C / 4; c4++) {
        uint2 pv = *reinterpret_cast<const uint2*>(hp + 4 * c4);
        float v0 = bfl(pv.x), v1 = bfh(pv.x), v2 = bfl(pv.y), v3 = bfh(pv.y);
        float4 a = ap[c4], b = bp[c4];
        s += v0 * a.x + v1 * a.y + v2 * a.z + v3 * a.w;
        d += v0 * b.x + v1 * b.y + v2 * b.z + v3 * b.w;
    }
    es[(size_t)hh * Nn + n] = s;
    ed[(size_t)hh * Nn + n] = d;
}

// ================= CSR build =================
__global__ void hist_kernel(const int* __restrict__ dst, int* __restrict__ counts,
                            int E0, int Etot) {
    int e = blockIdx.x * blockDim.x + threadIdx.x;
    if (e >= Etot) return;
    int d_ = (e < E0) ? dst[e] : e - E0;
    atomicAdd(&counts[d_], 1);
}

__global__ void scan_kernel(int* __restrict__ counts, int* __restrict__ row_ptr, int Nn) {
    __shared__ int wsum[16];
    __shared__ int chunk_total;
    __shared__ int carry_s;
    const int tid = threadIdx.x;
    const int lane = tid & 63;
    const int wid = tid >> 6;
    if (tid == 0) carry_s = 0;
    __syncthreads();
    for (int base = 0; base < Nn; base += 1024) {
        int i = base + tid;
        int v = (i < Nn) ? counts[i] : 0;
        int iv = v;
        #pragma unroll
        for (int off = 1; off < 64; off <<= 1) {
            int t = __shfl_up(iv, off, 64);
            if (lane >= off) iv += t;
        }
        if (lane == 63) wsum[wid] = iv;
        __syncthreads();
        if (tid == 0) {
            int s = 0;
            #pragma unroll
            for (int k = 0; k < 16; k++) { int t = wsum[k]; wsum[k] = s; s += t; }
            chunk_total = s;
        }
        __syncthreads();
        if (i < Nn) {
            int ex = carry_s + wsum[wid] + (iv - v);
            row_ptr[i] = ex;
            counts[i] = ex;
        }
        __syncthreads();
        if (tid == 0) carry_s += chunk_total;
        __syncthreads();
    }
    if (tid == 0) row_ptr[Nn] = carry_s;
}

__global__ void scatter_kernel(const int* __restrict__ src, const int* __restrict__ dst,
                               int* __restrict__ cursor, int* __restrict__ col,
                               int E0, int Etot) {
    int e = blockIdx.x * blockDim.x + threadIdx.x;
    if (e >= Etot) return;
    int d_ = (e < E0) ? dst[e] : e - E0;
    int s_ = (e < E0) ? src[e] : e - E0;
    int pos = atomicAdd(&cursor[d_], 1);
    col[pos] = s_;
}

// ========== fused softmax + aggregate + bias + ELU + BN (inline exp, no LDS) ==========
// NT lanes per (node, head), VEC = C/NT channels per lane.
// XCD affinity: head = blockIdx.x & 7 -> all blocks of one head land on one XCD
// (XCD = wgid % 8 round-robin), so that head's h slice (<= 3.2 MB) stays L2-resident.
template<int H, int C, int NT, int DO_ELU, int OUT_HILO>
__launch_bounds__(256)
__global__ void gat_fused(const int* __restrict__ row_ptr, const int* __restrict__ col,
                          const float* __restrict__ es, const float* __restrict__ ed,
                          const u16* __restrict__ h16, float* __restrict__ outf,
                          u16* __restrict__ outh, u16* __restrict__ outl,
                          const float* __restrict__ bias, const float* __restrict__ g,
                          const float* __restrict__ be, const float* __restrict__ rm,
                          const float* __restrict__ rv, int Nn) {
    constexpr int Dout = H * C;
    constexpr int VEC = C / NT;          // 8 (uint4) or 4 (uint2)
    constexpr int NPB = 256 / NT;
    const int tid = threadIdx.x;
    const int bx = blockIdx.x;
    const int hh = (H == 8) ? (bx & 7) : 0;
    const int nb = (H == 8) ? (bx >> 3) : bx;
    const int node = nb * NPB + tid / NT;
    const int t = tid % NT;
    if (node >= Nn) return;
    const int jb = row_ptr[node], je = row_ptr[node + 1];
    const float* esh = es + (size_t)hh * Nn;
    const float edv = ed[(size_t)hh * Nn + node];
    const u16* hb = h16 + (size_t)hh * Nn * C + t * VEC;
    float acc[VEC] = {};
    float den = 0.f;
    int j = jb;
    for (; j + 4 <= je; j += 4) {
        int s0 = col[j], s1 = col[j + 1], s2 = col[j + 2], s3 = col[j + 3];
        float e0 = esh[s0] + edv, e1 = esh[s1] + edv, e2 = esh[s2] + edv, e3 = esh[s3] + edv;
        e0 = (e0 >= 0.f) ? e0 : NEG_SLOPE * e0;
        e1 = (e1 >= 0.f) ? e1 : NEG_SLOPE * e1;
        e2 = (e2 >= 0.f) ? e2 : NEG_SLOPE * e2;
        e3 = (e3 >= 0.f) ? e3 : NEG_SLOPE * e3;
        float w0 = __expf(e0), w1 = __expf(e1), w2 = __expf(e2), w3 = __expf(e3);
        den += (w0 + w1) + (w2 + w3);
        if constexpr (VEC == 8) {
            uint4 p0 = *reinterpret_cast<const uint4*>(hb + (size_t)s0 * C);
            uint4 p1 = *reinterpret_cast<const uint4*>(hb + (size_t)s1 * C);
            uint4 p2 = *reinterpret_cast<const uint4*>(hb + (size_t)s2 * C);
            uint4 p3 = *reinterpret_cast<const uint4*>(hb + (size_t)s3 * C);
            acc[0] += w0 * bfl(p0.x) + w1 * bfl(p1.x) + w2 * bfl(p2.x) + w3 * bfl(p3.x);
            acc[1] += w0 * bfh(p0.x) + w1 * bfh(p1.x) + w2 * bfh(p2.x) + w3 * bfh(p3.x);
            acc[2] += w0 * bfl(p0.y) + w1 * bfl(p1.y) + w2 * bfl(p2.y) + w3 * bfl(p3.y);
            acc[3] += w0 * bfh(p0.y) + w1 * bfh(p1.y) + w2 * bfh(p2.y) + w3 * bfh(p3.y);
            acc[4] += w0 * bfl(p0.z) + w1 * bfl(p1.z) + w2 * bfl(p2.z) + w3 * bfl(p3.z);
            acc[5] += w0 * bfh(p0.z) + w1 * bfh(p1.z) + w2 * bfh(p2.z) + w3 * bfh(p3.z);
            acc[6] += w0 * bfl(p0.w) + w1 * bfl(p1.w) + w2 * bfl(p2.w) + w3 * bfl(p3.w);
            acc[7] += w0 * bfh(p0.w) + w1 * bfh(p1.w) + w2 * bfh(p2.w) + w3 * bfh(p3.w);
        } else {
            uint2 p0 = *reinterpret_cast<const uint2*>(hb + (size_t)s0 * C);
            uint2 p1 = *reinterpret_cast<const uint2*>(hb + (size_t)s1 * C);
            uint2 p2 = *reinterpret_cast<const uint2*>(hb + (size_t)s2 * C);
            uint2 p3 = *reinterpret_cast<const uint2*>(hb + (size_t)s3 * C);
            acc[0] += w0 * bfl(p0.x) + w1 * bfl(p1.x) + w2 * bfl(p2.x) + w3 * bfl(p3.x);
            acc[1] += w0 * bfh(p0.x) + w1 * bfh(p1.x) + w2 * bfh(p2.x) + w3 * bfh(p3.x);
            acc[2] += w0 * bfl(p0.y) + w1 * bfl(p1.y) + w2 * bfl(p2.y) + w3 * bfl(p3.y);
            acc[3] += w0 * bfh(p0.y) + w1 * bfh(p1.y) + w2 * bfh(p2.y) + w3 * bfh(p3.y);
        }
    }
    for (; j < je; j++) {
        int s = col[j];
        float a = esh[s] + edv;
        a = (a >= 0.f) ? a : NEG_SLOPE * a;
        float w = __expf(a);
        den += w;
        if constexpr (VEC == 8) {
            uint4 pv = *reinterpret_cast<const uint4*>(hb + (size_t)s * C);
            acc[0] += w * bfl(pv.x); acc[1] += w * bfh(pv.x);
            acc[2] += w * bfl(pv.y); acc[3] += w * bfh(pv.y);
            acc[4] += w * bfl(pv.z); acc[5] += w * bfh(pv.z);
            acc[6] += w * bfl(pv.w); acc[7] += w * bfh(pv.w);
        } else {
            uint2 pv = *reinterpret_cast<const uint2*>(hb + (size_t)s * C);
            acc[0] += w * bfl(pv.x); acc[1] += w * bfh(pv.x);
            acc[2] += w * bfl(pv.y); acc[3] += w * bfh(pv.y);
        }
    }
    const float inv = 1.f / (den + 1e-16f);
    const int jc = hh * C + t * VEC;
    float res[VEC];
    #pragma unroll
    for (int v = 0; v < VEC; v++) {
        float y = acc[v] * inv + bias[jc + v];
        if (DO_ELU) y = (y > 0.f) ? y : expm1f(y);
        y = (y - rm[jc + v]) * rsqrtf(rv[jc + v] + BN_EPS) * g[jc + v] + be[jc + v];
        res[v] = y;
    }
    if constexpr (OUT_HILO) {
        u32 rh[VEC], rl[VEC];
        #pragma unroll
        for (int v = 0; v < VEC; v++) {
            rh[v] = f2bf(res[v]);
            rl[v] = f2bf(res[v] - bf2f(rh[v]));
        }
        if constexpr (VEC == 8) {
            uint4 ph = make_uint4(rh[0] | (rh[1] << 16), rh[2] | (rh[3] << 16),
                                  rh[4] | (rh[5] << 16), rh[6] | (rh[7] << 16));
            uint4 pl = make_uint4(rl[0] | (rl[1] << 16), rl[2] | (rl[3] << 16),
                                  rl[4] | (rl[5] << 16), rl[6] | (rl[7] << 16));
            *reinterpret_cast<uint4*>(outh + (size_t)node * Dout + jc) = ph;
            *reinterpret_cast<uint4*>(outl + (size_t)node * Dout + jc) = pl;
        } else {
            uint2 ph = make_uint2(rh[0] | (rh[1] << 16), rh[2] | (rh[3] << 16));
            uint2 pl = make_uint2(rl[0] | (rl[1] << 16), rl[2] | (rl[3] << 16));
            *reinterpret_cast<uint2*>(outh + (size_t)node * Dout + jc) = ph;
            *reinterpret_cast<uint2*>(outl + (size_t)node * Dout + jc) = pl;
        }
    } else {
        float* op = outf + (size_t)node * Dout + jc;
        if constexpr (VEC == 8) {
            *reinterpret_cast<float4*>(op) = make_float4(res[0], res[1], res[2], res[3]);
            *reinterpret_cast<float4*>(op + 4) = make_float4(res[4], res[5], res[6], res[7]);
        } else {
            *reinterpret_cast<float4*>(op) = make_float4(res[0], res[1], res[2], res[3]);
        }
    }
}

extern "C" void kernel_launch(void* const* d_in, const int* in_sizes, int n_in,
                              void* d_out, int out_size, void* d_ws, size_t ws_size,
                              hipStream_t stream) {
    const float* x = (const float*)d_in[0];
    const int* src = (const int*)d_in[1];
    const int* dst = (const int*)d_in[2];
    const int Nn = in_sizes[0] / 128;   // 50000
    const int E0 = in_sizes[1];         // 400000
    const int Etot = E0 + Nn;

    // ---- workspace layout ----
    u16* A0 = (u16*)d_ws;                                  // Nn*512 u16: Y1H/Y1L or out3 fp32
    u16* Bh = A0 + (size_t)Nn * 512;                       // Nn*256 u16: h (head-major)
    u16* Ch = Bh + (size_t)Nn * 256;                       // Nn*256 u16: Y2H/Y2L
    float* es = (float*)(Ch + (size_t)Nn * 256);           // Nn*8 (head-major)
    float* ed = es + (size_t)Nn * 8;                       // Nn*8
    int* row_ptr = (int*)(ed + (size_t)Nn * 8);            // Nn+1
    int* cursor  = row_ptr + (Nn + 1);                     // Nn
    int* col     = cursor + Nn;                            // Etot
    u16* wth1 = (u16*)(col + Etot);
    u16* wtl1 = wth1 + 32768;
    u16* wth2 = wtl1 + 32768;
    u16* wtl2 = wth2 + 32768;
    u16* wth3 = wtl2 + 32768;
    u16* wtl3 = wth3 + 8192;

    u16* Y1H = A0;
    u16* Y1L = A0 + (size_t)Nn * 256;
    u16* Y2H = Ch;
    u16* Y2L = Ch + (size_t)Nn * 128;
    float* out3 = (float*)A0;

    // ---- CSR build ----
    hipMemsetAsync(cursor, 0, sizeof(int) * Nn, stream);
    hist_kernel<<<(Etot + 255) / 256, 256, 0, stream>>>(dst, cursor, E0, Etot);
    scan_kernel<<<1, 1024, 0, stream>>>(cursor, row_ptr, Nn);
    scatter_kernel<<<(Etot + 255) / 256, 256, 0, stream>>>(src, dst, cursor, col, E0, Etot);

    const int gy128 = (Nn + 127) / 128;

    const float* const* p1 = (const float* const*)(d_in + 3);
    const float* const* p2 = (const float* const*)(d_in + 11);
    const float* const* p3 = (const float* const*)(d_in + 19);
    const float* const* p4 = (const float* const*)(d_in + 27);

    wt_prep3<<<288, 256, 0, stream>>>(p1[0], p2[0], p3[0], wth1, wtl1, wth2, wtl2, wth3, wtl3);

    // ---------------- layer 1: K=128 -> Dout=256 (H=8,C=32) ----------------
    gemm_mfma<128, 32, 1><<<dim3(2, gy128), 256, 0, stream>>>(x, nullptr, wth1, wtl1, Bh, Nn, 128, 256);
    scores_kernel<<<(Nn * 8 + 255) / 256, 256, 0, stream>>>(Bh, p1[1], p1[2], es, ed, Nn, 8, 32);
    gat_fused<8, 32, 4, 1, 1><<<dim3(((Nn + 63) / 64) * 8), 256, 0, stream>>>(
        row_ptr, col, es, ed, Bh, nullptr, Y1H, Y1L, p1[3], p1[4], p1[5], p1[6], p1[7], Nn);

    // ---------------- layer 2: K=256 -> Dout=128 (H=8,C=16) ----------------
    gemm_mfma<128, 16, 0><<<dim3(1, gy128), 256, 0, stream>>>(Y1H, Y1L, wth2, wtl2, Bh, Nn, 256, 128);
    scores_kernel<<<(Nn * 8 + 255) / 256, 256, 0, stream>>>(Bh, p2[1], p2[2], es, ed, Nn, 8, 16);
    gat_fused<8, 16, 2, 1, 1><<<dim3(((Nn + 127) / 128) * 8), 256, 0, stream>>>(
        row_ptr, col, es, ed, Bh, nullptr, Y2H, Y2L, p2[3], p2[4], p2[5], p2[6], p2[7], Nn);

    // ---------------- layer 3: K=128 -> Dout=64 (H=8,C=8) ----------------
    gemm_mfma<64, 8, 0><<<dim3(1, gy128), 256, 0, stream>>>(Y2H, Y2L, wth3, wtl3, Bh, Nn, 128, 64);
    scores_kernel<<<(Nn * 8 + 255) / 256, 256, 0, stream>>>(Bh, p3[1], p3[2], es, ed, Nn, 8, 8);
    gat_fused<8, 8, 2, 1, 0><<<dim3(((Nn + 127) / 128) * 8), 256, 0, stream>>>(
        row_ptr, col, es, ed, Bh, out3, nullptr, nullptr, p3[3], p3[4], p3[5], p3[6], p3[7], Nn);

    // ---------------- layer 4: K=64 -> Dout=16 (H=1,C=16) ----------------
    gemm_k64n16<<<(Nn + 63) / 64, 256, 0, stream>>>(out3, p4[0], Bh, Nn);
    scores_kernel<<<(Nn + 255) / 256, 256, 0, stream>>>(Bh, p4[1], p4[2], es, ed, Nn, 1, 16);
    gat_fused<1, 16, 2, 0, 0><<<dim3((Nn + 127) / 128), 256, 0, stream>>>(
        row_ptr, col, es, ed, Bh, (float*)d_out, nullptr, nullptr, p4[3], p4[4], p4[5], p4[6], p4[7], Nn);
}

// Round 18
// 375.169 us; speedup vs baseline: 2.0438x; 1.0018x over previous
//
#include <hip/hip_runtime.h>

#define NEG_SLOPE 0.2f
#define BN_EPS 1e-5f

typedef unsigned short u16;
typedef unsigned int u32;
typedef __bf16 bf16x8 __attribute__((ext_vector_type(8)));
typedef float f32x4 __attribute__((ext_vector_type(4)));

__device__ __forceinline__ u32 f2bf(float f) {
    u32 u = __float_as_uint(f);
    return (u + 0x7FFFu + ((u >> 16) & 1u)) >> 16;
}
__device__ __forceinline__ float bf2f(u32 h) { return __uint_as_float(h << 16); }
__device__ __forceinline__ float bfl(u32 p) { return __uint_as_float(p << 16); }
__device__ __forceinline__ float bfh(u32 p) { return __uint_as_float(p & 0xFFFF0000u); }

__device__ __forceinline__ void split8(const float4 f0, const float4 f1, uint4& vh, uint4& vl) {
    float f[8] = {f0.x, f0.y, f0.z, f0.w, f1.x, f1.y, f1.z, f1.w};
    u32 h[8], l[8];
    #pragma unroll
    for (int i = 0; i < 8; i++) { h[i] = f2bf(f[i]); l[i] = f2bf(f[i] - bf2f(h[i])); }
    vh = make_uint4(h[0] | (h[1] << 16), h[2] | (h[3] << 16), h[4] | (h[5] << 16), h[6] | (h[7] << 16));
    vl = make_uint4(l[0] | (l[1] << 16), l[2] | (l[3] << 16), l[4] | (l[5] << 16), l[6] | (l[7] << 16));
}

// ========== weight prep for layers 1-3 in one dispatch ==========
__global__ void wt_prep3(const float* __restrict__ W1, const float* __restrict__ W2,
                         const float* __restrict__ W3,
                         u16* __restrict__ h1, u16* __restrict__ l1,
                         u16* __restrict__ h2, u16* __restrict__ l2,
                         u16* __restrict__ h3, u16* __restrict__ l3) {
    int i = blockIdx.x * blockDim.x + threadIdx.x;
    const float* W; u16 *ph, *pl; int K, N, off;
    if (i < 32768)      { W = W1; ph = h1; pl = l1; K = 128; N = 256; off = i; }
    else if (i < 65536) { W = W2; ph = h2; pl = l2; K = 256; N = 128; off = i - 32768; }
    else if (i < 73728) { W = W3; ph = h3; pl = l3; K = 128; N = 64;  off = i - 65536; }
    else return;
    int k = off / N, n = off - k * N;
    float w = W[off];
    u32 h = f2bf(w);
    ph[n * K + k] = (u16)h;
    pl[n * K + k] = (u16)f2bf(w - bf2f(h));
}

// ========== split-bf16 MFMA GEMM -> bf16 head-major output ==========
// AF32=1: A is fp32 [M][K], hi/lo split in-register while staging.
template<int BN, int HMC, int AF32>
__launch_bounds__(256)
__global__ void gemm_mfma(const void* __restrict__ A_, const u16* __restrict__ Alo,
                          const u16* __restrict__ Bhi, const u16* __restrict__ Blo,
                          u16* __restrict__ Cbf, int M, int K, int N) {
    constexpr int FM = (BN == 128) ? 4 : 2;
    __shared__ uint4 sA[2][512];
    __shared__ uint4 sB[2][BN * 4];
    const int tid = threadIdx.x;
    const int bm = blockIdx.y * 128;
    const int bn = blockIdx.x * BN;
    const int lane = tid & 63;
    const int w = tid >> 6;
    const int wm = (BN == 128) ? (w >> 1) * 64 : w * 32;
    const int wn = (BN == 128) ? (w & 1) * 64 : 0;
    const int fr = lane & 15;
    const int fs = lane >> 4;
    f32x4 zero = {0.f, 0.f, 0.f, 0.f};
    f32x4 acc[FM][4];
    #pragma unroll
    for (int i = 0; i < FM; i++)
        #pragma unroll
        for (int j = 0; j < 4; j++) acc[i][j] = zero;

    const int r0 = tid >> 2;
    const int ss = tid & 3;
    const int r1 = r0 + 64;
    const int d0 = r0 * 4 + (ss ^ ((r0 >> 1) & 3));
    const int d1 = r1 * 4 + (ss ^ ((r1 >> 1) & 3));

    for (int k0 = 0; k0 < K; k0 += 32) {
        if constexpr (AF32) {
            const float* Af = (const float*)A_;
            int gr = bm + r0;
            uint4 vh = make_uint4(0,0,0,0), vl = make_uint4(0,0,0,0);
            if (gr < M) {
                float4 f0 = *(const float4*)(Af + (size_t)gr * K + k0 + ss * 8);
                float4 f1 = *(const float4*)(Af + (size_t)gr * K + k0 + ss * 8 + 4);
                split8(f0, f1, vh, vl);
            }
            sA[0][d0] = vh; sA[1][d0] = vl;
            gr = bm + r1;
            vh = make_uint4(0,0,0,0); vl = make_uint4(0,0,0,0);
            if (gr < M) {
                float4 f0 = *(const float4*)(Af + (size_t)gr * K + k0 + ss * 8);
                float4 f1 = *(const float4*)(Af + (size_t)gr * K + k0 + ss * 8 + 4);
                split8(f0, f1, vh, vl);
            }
            sA[0][d1] = vh; sA[1][d1] = vl;
        } else {
            const u16* Ahi = (const u16*)A_;
            int gr = bm + r0;
            uint4 vh = make_uint4(0,0,0,0), vl = make_uint4(0,0,0,0);
            if (gr < M) {
                vh = *(const uint4*)(Ahi + (size_t)gr * K + k0 + ss * 8);
                vl = *(const uint4*)(Alo + (size_t)gr * K + k0 + ss * 8);
            }
            sA[0][d0] = vh; sA[1][d0] = vl;
            gr = bm + r1;
            vh = make_uint4(0,0,0,0); vl = make_uint4(0,0,0,0);
            if (gr < M) {
                vh = *(const uint4*)(Ahi + (size_t)gr * K + k0 + ss * 8);
                vl = *(const uint4*)(Alo + (size_t)gr * K + k0 + ss * 8);
            }
            sA[0][d1] = vh; sA[1][d1] = vl;
        }
        {
            int gr = bn + r0;
            sB[0][d0] = *(const uint4*)(Bhi + (size_t)gr * K + k0 + ss * 8);
            sB[1][d0] = *(const uint4*)(Blo + (size_t)gr * K + k0 + ss * 8);
            if constexpr (BN == 128) {
                gr = bn + r1;
                sB[0][d1] = *(const uint4*)(Bhi + (size_t)gr * K + k0 + ss * 8);
                sB[1][d1] = *(const uint4*)(Blo + (size_t)gr * K + k0 + ss * 8);
            }
        }
        __syncthreads();
        bf16x8 ah[FM], al[FM], bh[4], bl[4];
        #pragma unroll
        for (int mi = 0; mi < FM; mi++) {
            int row = wm + mi * 16 + fr;
            int idx = row * 4 + (fs ^ ((row >> 1) & 3));
            ah[mi] = *reinterpret_cast<const bf16x8*>(&sA[0][idx]);
            al[mi] = *reinterpret_cast<const bf16x8*>(&sA[1][idx]);
        }
        #pragma unroll
        for (int ni = 0; ni < 4; ni++) {
            int row = wn + ni * 16 + fr;
            int idx = row * 4 + (fs ^ ((row >> 1) & 3));
            bh[ni] = *reinterpret_cast<const bf16x8*>(&sB[0][idx]);
            bl[ni] = *reinterpret_cast<const bf16x8*>(&sB[1][idx]);
        }
        #pragma unroll
        for (int mi = 0; mi < FM; mi++)
            #pragma unroll
            for (int ni = 0; ni < 4; ni++) {
                acc[mi][ni] = __builtin_amdgcn_mfma_f32_16x16x32_bf16(ah[mi], bh[ni], acc[mi][ni], 0, 0, 0);
                acc[mi][ni] = __builtin_amdgcn_mfma_f32_16x16x32_bf16(ah[mi], bl[ni], acc[mi][ni], 0, 0, 0);
                acc[mi][ni] = __builtin_amdgcn_mfma_f32_16x16x32_bf16(al[mi], bh[ni], acc[mi][ni], 0, 0, 0);
            }
        __syncthreads();
    }
    #pragma unroll
    for (int mi = 0; mi < FM; mi++) {
        #pragma unroll
        for (int ni = 0; ni < 4; ni++) {
            int colg = bn + wn + ni * 16 + fr;
            int rbase = bm + wm + mi * 16 + fs * 4;
            #pragma unroll
            for (int r = 0; r < 4; r++) {
                int rw = rbase + r;
                if (rw >= M) continue;
                u16 val = (u16)f2bf(acc[mi][ni][r]);
                if constexpr (HMC > 0) {
                    int hh2 = colg / HMC, cc2 = colg - hh2 * HMC;
                    Cbf[((size_t)hh2 * M + rw) * HMC + cc2] = val;
                } else {
                    Cbf[(size_t)rw * N + colg] = val;
                }
            }
        }
    }
}

// ================= small GEMM for layer 4: K=64, N=16 -> bf16 out =================
__launch_bounds__(256)
__global__ void gemm_k64n16(const float* __restrict__ A, const float* __restrict__ B,
                            u16* __restrict__ Cbf, int M) {
    __shared__ float As[64][68];
    __shared__ float Bs[64][16];
    const int tid = threadIdx.x;
    const int bm = blockIdx.x * 64;
    {
        int r = tid >> 2, c = (tid & 3) << 2;
        *reinterpret_cast<float4*>(&Bs[r][c]) = *reinterpret_cast<const float4*>(&B[r * 16 + c]);
    }
    #pragma unroll
    for (int p = 0; p < 4; p++) {
        int m = (tid >> 4) + p * 16;
        int c = (tid & 15) << 2;
        int gm = bm + m;
        float4 v = make_float4(0.f, 0.f, 0.f, 0.f);
        if (gm < M) v = *reinterpret_cast<const float4*>(&A[(size_t)gm * 64 + c]);
        *reinterpret_cast<float4*>(&As[m][c]) = v;
    }
    __syncthreads();
    const int tc = tid & 15;
    const int r0 = tid >> 4;
    float acc[4] = {};
    #pragma unroll
    for (int k4 = 0; k4 < 16; k4++) {
        float b0 = Bs[4 * k4 + 0][tc];
        float b1 = Bs[4 * k4 + 1][tc];
        float b2 = Bs[4 * k4 + 2][tc];
        float b3 = Bs[4 * k4 + 3][tc];
        #pragma unroll
        for (int i = 0; i < 4; i++) {
            float4 av = *reinterpret_cast<const float4*>(&As[r0 + i * 16][4 * k4]);
            acc[i] += av.x * b0 + av.y * b1 + av.z * b2 + av.w * b3;
        }
    }
    #pragma unroll
    for (int i = 0; i < 4; i++) {
        int m = bm + r0 + i * 16;
        if (m < M) Cbf[(size_t)m * 16 + tc] = (u16)f2bf(acc[i]);
    }
}

// ========== per-node attention scores (head-major h; head-major es/ed) ==========
__global__ void scores_kernel(const u16* __restrict__ h,
                              const float* __restrict__ asrc,
                              const float* __restrict__ adst,
                              float* __restrict__ es, float* __restrict__ ed,
                              int Nn, int H, int C) {
    int idx = blockIdx.x * blockDim.x + threadIdx.x;
    if (idx >= Nn * H) return;
    int n = idx / H, hh = idx % H;
    const u16* hp = h + ((size_t)hh * Nn + n) * C;
    const float4* ap = reinterpret_cast<const float4*>(asrc + hh * C);
    const float4* bp = reinterpret_cast<const float4*>(adst + hh * C);
    float s = 0.f, d = 0.f;
    for (int c4 = 0; c4 < C / 4; c4++) {
        uint2 pv = *reinterpret_cast<const uint2*>(hp + 4 * c4);
        float v0 = bfl(pv.x), v1 = bfh(pv.x), v2 = bfl(pv.y), v3 = bfh(pv.y);
        float4 a = ap[c4], b = bp[c4];
        s += v0 * a.x + v1 * a.y + v2 * a.z + v3 * a.w;
        d += v0 * b.x + v1 * b.y + v2 * b.z + v3 * b.w;
    }
    es[(size_t)hh * Nn + n] = s;
    ed[(size_t)hh * Nn + n] = d;
}

// ================= CSR build =================
__global__ void hist_kernel(const int* __restrict__ dst, int* __restrict__ counts,
                            int E0, int Etot) {
    int e = blockIdx.x * blockDim.x + threadIdx.x;
    if (e >= Etot) return;
    int d_ = (e < E0) ? dst[e] : e - E0;
    atomicAdd(&counts[d_], 1);
}

__global__ void scan_kernel(int* __restrict__ counts, int* __restrict__ row_ptr, int Nn) {
    __shared__ int wsum[16];
    __shared__ int chunk_total;
    __shared__ int carry_s;
    const int tid = threadIdx.x;
    const int lane = tid & 63;
    const int wid = tid >> 6;
    if (tid == 0) carry_s = 0;
    __syncthreads();
    for (int base = 0; base < Nn; base += 1024) {
        int i = base + tid;
        int v = (i < Nn) ? counts[i] : 0;
        int iv = v;
        #pragma unroll
        for (int off = 1; off < 64; off <<= 1) {
            int t = __shfl_up(iv, off, 64);
            if (lane >= off) iv += t;
        }
        if (lane == 63) wsum[wid] = iv;
        __syncthreads();
        if (tid == 0) {
            int s = 0;
            #pragma unroll
            for (int k = 0; k < 16; k++) { int t = wsum[k]; wsum[k] = s; s += t; }
            chunk_total = s;
        }
        __syncthreads();
        if (i < Nn) {
            int ex = carry_s + wsum[wid] + (iv - v);
            row_ptr[i] = ex;
            counts[i] = ex;
        }
        __syncthreads();
        if (tid == 0) carry_s += chunk_total;
        __syncthreads();
    }
    if (tid == 0) row_ptr[Nn] = carry_s;
}

__global__ void scatter_kernel(const int* __restrict__ src, const int* __restrict__ dst,
                               int* __restrict__ cursor, int* __restrict__ col,
                               int E0, int Etot) {
    int e = blockIdx.x * blockDim.x + threadIdx.x;
    if (e >= Etot) return;
    int d_ = (e < E0) ? dst[e] : e - E0;
    int s_ = (e < E0) ? src[e] : e - E0;
    int pos = atomicAdd(&cursor[d_], 1);
    col[pos] = s_;
}

// ========== fused softmax + aggregate + bias + ELU + BN (inline exp, no LDS) ==========
// NT lanes per (node, head), VEC = C/NT channels per lane.
// XCD affinity: head = blockIdx.x & 7 -> all blocks of one head land on one XCD
// (XCD = wgid % 8 round-robin), so that head's h slice (<= 3.2 MB) stays L2-resident.
template<int H, int C, int NT, int DO_ELU, int OUT_HILO>
__launch_bounds__(256)
__global__ void gat_fused(const int* __restrict__ row_ptr, const int* __restrict__ col,
                          const float* __restrict__ es, const float* __restrict__ ed,
                          const u16* __restrict__ h16, float* __restrict__ outf,
                          u16* __restrict__ outh, u16* __restrict__ outl,
                          const float* __restrict__ bias, const float* __restrict__ g,
                          const float* __restrict__ be, const float* __restrict__ rm,
                          const float* __restrict__ rv, int Nn) {
    constexpr int Dout = H * C;
    constexpr int VEC = C / NT;          // 8 (uint4) or 4 (uint2)
    constexpr int NPB = 256 / NT;
    const int tid = threadIdx.x;
    const int bx = blockIdx.x;
    const int hh = (H == 8) ? (bx & 7) : 0;
    const int nb = (H == 8) ? (bx >> 3) : bx;
    const int node = nb * NPB + tid / NT;
    const int t = tid % NT;
    if (node >= Nn) return;
    const int jb = row_ptr[node], je = row_ptr[node + 1];
    const float* esh = es + (size_t)hh * Nn;
    const float edv = ed[(size_t)hh * Nn + node];
    const u16* hb = h16 + (size_t)hh * Nn * C + t * VEC;
    float acc[VEC] = {};
    float den = 0.f;
    int j = jb;
    for (; j + 4 <= je; j += 4) {
        int s0 = col[j], s1 = col[j + 1], s2 = col[j + 2], s3 = col[j + 3];
        float e0 = esh[s0] + edv, e1 = esh[s1] + edv, e2 = esh[s2] + edv, e3 = esh[s3] + edv;
        e0 = (e0 >= 0.f) ? e0 : NEG_SLOPE * e0;
        e1 = (e1 >= 0.f) ? e1 : NEG_SLOPE * e1;
        e2 = (e2 >= 0.f) ? e2 : NEG_SLOPE * e2;
        e3 = (e3 >= 0.f) ? e3 : NEG_SLOPE * e3;
        float w0 = __expf(e0), w1 = __expf(e1), w2 = __expf(e2), w3 = __expf(e3);
        den += (w0 + w1) + (w2 + w3);
        if constexpr (VEC == 8) {
            uint4 p0 = *reinterpret_cast<const uint4*>(hb + (size_t)s0 * C);
            uint4 p1 = *reinterpret_cast<const uint4*>(hb + (size_t)s1 * C);
            uint4 p2 = *reinterpret_cast<const uint4*>(hb + (size_t)s2 * C);
            uint4 p3 = *reinterpret_cast<const uint4*>(hb + (size_t)s3 * C);
            acc[0] += w0 * bfl(p0.x) + w1 * bfl(p1.x) + w2 * bfl(p2.x) + w3 * bfl(p3.x);
            acc[1] += w0 * bfh(p0.x) + w1 * bfh(p1.x) + w2 * bfh(p2.x) + w3 * bfh(p3.x);
            acc[2] += w0 * bfl(p0.y) + w1 * bfl(p1.y) + w2 * bfl(p2.y) + w3 * bfl(p3.y);
            acc[3] += w0 * bfh(p0.y) + w1 * bfh(p1.y) + w2 * bfh(p2.y) + w3 * bfh(p3.y);
            acc[4] += w0 * bfl(p0.z) + w1 * bfl(p1.z) + w2 * bfl(p2.z) + w3 * bfl(p3.z);
            acc[5] += w0 * bfh(p0.z) + w1 * bfh(p1.z) + w2 * bfh(p2.z) + w3 * bfh(p3.z);
            acc[6] += w0 * bfl(p0.w) + w1 * bfl(p1.w) + w2 * bfl(p2.w) + w3 * bfl(p3.w);
            acc[7] += w0 * bfh(p0.w) + w1 * bfh(p1.w) + w2 * bfh(p2.w) + w3 * bfh(p3.w);
        } else {
            uint2 p0 = *reinterpret_cast<const uint2*>(hb + (size_t)s0 * C);
            uint2 p1 = *reinterpret_cast<const uint2*>(hb + (size_t)s1 * C);
            uint2 p2 = *reinterpret_cast<const uint2*>(hb + (size_t)s2 * C);
            uint2 p3 = *reinterpret_cast<const uint2*>(hb + (size_t)s3 * C);
            acc[0] += w0 * bfl(p0.x) + w1 * bfl(p1.x) + w2 * bfl(p2.x) + w3 * bfl(p3.x);
            acc[1] += w0 * bfh(p0.x) + w1 * bfh(p1.x) + w2 * bfh(p2.x) + w3 * bfh(p3.x);
            acc[2] += w0 * bfl(p0.y) + w1 * bfl(p1.y) + w2 * bfl(p2.y) + w3 * bfl(p3.y);
            acc[3] += w0 * bfh(p0.y) + w1 * bfh(p1.y) + w2 * bfh(p2.y) + w3 * bfh(p3.y);
        }
    }
    for (; j < je; j++) {
        int s = col[j];
        float a = esh[s] + edv;
        a = (a >= 0.f) ? a : NEG_SLOPE * a;
        float w = __expf(a);
        den += w;
        if constexpr (VEC == 8) {
            uint4 pv = *reinterpret_cast<const uint4*>(hb + (size_t)s * C);
            acc[0] += w * bfl(pv.x); acc[1] += w * bfh(pv.x);
            acc[2] += w * bfl(pv.y); acc[3] += w * bfh(pv.y);
            acc[4] += w * bfl(pv.z); acc[5] += w * bfh(pv.z);
            acc[6] += w * bfl(pv.w); acc[7] += w * bfh(pv.w);
        } else {
            uint2 pv = *reinterpret_cast<const uint2*>(hb + (size_t)s * C);
            acc[0] += w * bfl(pv.x); acc[1] += w * bfh(pv.x);
            acc[2] += w * bfl(pv.y); acc[3] += w * bfh(pv.y);
        }
    }
    const float inv = 1.f / (den + 1e-16f);
    const int jc = hh * C + t * VEC;
    float res[VEC];
    #pragma unroll
    for (int v = 0; v < VEC; v++) {
        float y = acc[v] * inv + bias[jc + v];
        if (DO_ELU) y = (y > 0.f) ? y : expm1f(y);
        y = (y - rm[jc + v]) * rsqrtf(rv[jc + v] + BN_EPS) * g[jc + v] + be[jc + v];
        res[v] = y;
    }
    if constexpr (OUT_HILO) {
        u32 rh[VEC], rl[VEC];
        #pragma unroll
        for (int v = 0; v < VEC; v++) {
            rh[v] = f2bf(res[v]);
            rl[v] = f2bf(res[v] - bf2f(rh[v]));
        }
        if constexpr (VEC == 8) {
            uint4 ph = make_uint4(rh[0] | (rh[1] << 16), rh[2] | (rh[3] << 16),
                                  rh[4] | (rh[5] << 16), rh[6] | (rh[7] << 16));
            uint4 pl = make_uint4(rl[0] | (rl[1] << 16), rl[2] | (rl[3] << 16),
                                  rl[4] | (rl[5] << 16), rl[6] | (rl[7] << 16));
            *reinterpret_cast<uint4*>(outh + (size_t)node * Dout + jc) = ph;
            *reinterpret_cast<uint4*>(outl + (size_t)node * Dout + jc) = pl;
        } else {
            uint2 ph = make_uint2(rh[0] | (rh[1] << 16), rh[2] | (rh[3] << 16));
            uint2 pl = make_uint2(rl[0] | (rl[1] << 16), rl[2] | (rl[3] << 16));
            *reinterpret_cast<uint2*>(outh + (size_t)node * Dout + jc) = ph;
            *reinterpret_cast<uint2*>(outl + (size_t)node * Dout + jc) = pl;
        }
    } else {
        float* op = outf + (size_t)node * Dout + jc;
        if constexpr (VEC == 8) {
            *reinterpret_cast<float4*>(op) = make_float4(res[0], res[1], res[2], res[3]);
            *reinterpret_cast<float4*>(op + 4) = make_float4(res[4], res[5], res[6], res[7]);
        } else {
            *reinterpret_cast<float4*>(op) = make_float4(res[0], res[1], res[2], res[3]);
        }
    }
}

extern "C" void kernel_launch(void* const* d_in, const int* in_sizes, int n_in,
                              void* d_out, int out_size, void* d_ws, size_t ws_size,
                              hipStream_t stream) {
    const float* x = (const float*)d_in[0];
    const int* src = (const int*)d_in[1];
    const int* dst = (const int*)d_in[2];
    const int Nn = in_sizes[0] / 128;   // 50000
    const int E0 = in_sizes[1];         // 400000
    const int Etot = E0 + Nn;

    // ---- workspace layout ----
    u16* A0 = (u16*)d_ws;                                  // Nn*512 u16: Y1H/Y1L or out3 fp32
    u16* Bh = A0 + (size_t)Nn * 512;                       // Nn*256 u16: h (head-major)
    u16* Ch = Bh + (size_t)Nn * 256;                       // Nn*256 u16: Y2H/Y2L
    float* es = (float*)(Ch + (size_t)Nn * 256);           // Nn*8 (head-major)
    float* ed = es + (size_t)Nn * 8;                       // Nn*8
    int* row_ptr = (int*)(ed + (size_t)Nn * 8);            // Nn+1
    int* cursor  = row_ptr + (Nn + 1);                     // Nn
    int* col     = cursor + Nn;                            // Etot
    u16* wth1 = (u16*)(col + Etot);
    u16* wtl1 = wth1 + 32768;
    u16* wth2 = wtl1 + 32768;
    u16* wtl2 = wth2 + 32768;
    u16* wth3 = wtl2 + 32768;
    u16* wtl3 = wth3 + 8192;

    u16* Y1H = A0;
    u16* Y1L = A0 + (size_t)Nn * 256;
    u16* Y2H = Ch;
    u16* Y2L = Ch + (size_t)Nn * 128;
    float* out3 = (float*)A0;

    // ---- CSR build ----
    hipMemsetAsync(cursor, 0, sizeof(int) * Nn, stream);
    hist_kernel<<<(Etot + 255) / 256, 256, 0, stream>>>(dst, cursor, E0, Etot);
    scan_kernel<<<1, 1024, 0, stream>>>(cursor, row_ptr, Nn);
    scatter_kernel<<<(Etot + 255) / 256, 256, 0, stream>>>(src, dst, cursor, col, E0, Etot);

    const int gy128 = (Nn + 127) / 128;

    const float* const* p1 = (const float* const*)(d_in + 3);
    const float* const* p2 = (const float* const*)(d_in + 11);
    const float* const* p3 = (const float* const*)(d_in + 19);
    const float* const* p4 = (const float* const*)(d_in + 27);

    wt_prep3<<<288, 256, 0, stream>>>(p1[0], p2[0], p3[0], wth1, wtl1, wth2, wtl2, wth3, wtl3);

    // ---------------- layer 1: K=128 -> Dout=256 (H=8,C=32) ----------------
    gemm_mfma<128, 32, 1><<<dim3(2, gy128), 256, 0, stream>>>(x, nullptr, wth1, wtl1, Bh, Nn, 128, 256);
    scores_kernel<<<(Nn * 8 + 255) / 256, 256, 0, stream>>>(Bh, p1[1], p1[2], es, ed, Nn, 8, 32);
    gat_fused<8, 32, 4, 1, 1><<<dim3(((Nn + 63) / 64) * 8), 256, 0, stream>>>(
        row_ptr, col, es, ed, Bh, nullptr, Y1H, Y1L, p1[3], p1[4], p1[5], p1[6], p1[7], Nn);

    // ---------------- layer 2: K=256 -> Dout=128 (H=8,C=16) ----------------
    gemm_mfma<128, 16, 0><<<dim3(1, gy128), 256, 0, stream>>>(Y1H, Y1L, wth2, wtl2, Bh, Nn, 256, 128);
    scores_kernel<<<(Nn * 8 + 255) / 256, 256, 0, stream>>>(Bh, p2[1], p2[2], es, ed, Nn, 8, 16);
    gat_fused<8, 16, 2, 1, 1><<<dim3(((Nn + 127) / 128) * 8), 256, 0, stream>>>(
        row_ptr, col, es, ed, Bh, nullptr, Y2H, Y2L, p2[3], p2[4], p2[5], p2[6], p2[7], Nn);

    // ---------------- layer 3: K=128 -> Dout=64 (H=8,C=8) ----------------
    gemm_mfma<64, 8, 0><<<dim3(1, gy128), 256, 0, stream>>>(Y2H, Y2L, wth3, wtl3, Bh, Nn, 128, 64);
    scores_kernel<<<(Nn * 8 + 255) / 256, 256, 0, stream>>>(Bh, p3[1], p3[2], es, ed, Nn, 8, 8);
    gat_fused<8, 8, 2, 1, 0><<<dim3(((Nn + 127) / 128) * 8), 256, 0, stream>>>(
        row_ptr, col, es, ed, Bh, out3, nullptr, nullptr, p3[3], p3[4], p3[5], p3[6], p3[7], Nn);

    // ---------------- layer 4: K=64 -> Dout=16 (H=1,C=16) ----------------
    gemm_k64n16<<<(Nn + 63) / 64, 256, 0, stream>>>(out3, p4[0], Bh, Nn);
    scores_kernel<<<(Nn + 255) / 256, 256, 0, stream>>>(Bh, p4[1], p4[2], es, ed, Nn, 1, 16);
    gat_fused<1, 16, 2, 0, 0><<<dim3((Nn + 127) / 128), 256, 0, stream>>>(
        row_ptr, col, es, ed, Bh, (float*)d_out, nullptr, nullptr, p4[3], p4[4], p4[5], p4[6], p4[7], Nn);
}